// Round 1
// baseline (2894.303 us; speedup 1.0000x reference)
//
#include <hip/hip_runtime.h>
#include <hip/hip_bf16.h>

#define N_NODES 500000
#define E_EDGES 500000
#define FDIM 128
#define BN_EPS 1e-3f

// ws layout (in floats):
//   [0, 16384)           buckets: 64 x (sum[128], sumsq[128])
//   [16384, 16640)       scaleshift: scale[128], shift[128]
//   [16640, 82176)       pack_gru  [128][128][4]  ({z,r,h,pad} per (k,c))
//   [82176, 147712)      pack_rec  [128][128][4]
//   [147712, +64e6)      prev_sum  [N][128]
#define WS_BUCKETS 0
#define WS_SCALESHIFT 16384
#define WS_PACK_GRU 16640
#define WS_PACK_REC 82176
#define WS_PREV 147712

// ---------------------------------------------------------------- repack
__global__ __launch_bounds__(256) void repack_kernel(
    const float* __restrict__ gk, const float* __restrict__ rk,
    float* __restrict__ pg, float* __restrict__ pr) {
  int i = blockIdx.x * 256 + threadIdx.x;   // 0..16383
  int k = i >> 7, c = i & 127;
  float4 g = make_float4(gk[k * 384 + c], gk[k * 384 + 128 + c],
                         gk[k * 384 + 256 + c], 0.f);
  float4 r = make_float4(rk[k * 384 + c], rk[k * 384 + 128 + c],
                         rk[k * 384 + 256 + c], 0.f);
  ((float4*)pg)[i] = g;
  ((float4*)pr)[i] = r;
}

// ---------------------------------------------------------------- scatter-add
// one block = 2 edges; 128 threads per edge (one per feature)
__global__ __launch_bounds__(256) void scatter_kernel(
    const int* __restrict__ pp, const int* __restrict__ pn,
    const float* __restrict__ x, float* prev_sum, float* next_sum) {
  int e = blockIdx.x * 2 + (threadIdx.x >> 7);
  int f = threadIdx.x & 127;
  const int* pair;
  float* dst;
  if (e < E_EDGES) {
    pair = pp + 2 * e;
    dst = prev_sum;
  } else {
    pair = pn + 2 * (e - E_EDGES);
    dst = next_sum;
  }
  int d = pair[0], s = pair[1];
  atomicAdd(dst + (size_t)d * FDIM + f, x[(size_t)s * FDIM + f]);
}

// ---------------------------------------------------------------- aggre + relu + BN-stats
// block: 256 threads, 32 rows. thread: cols {c2, c2+64}, rows ty*8..ty*8+7
// NOTE: next_sum and a_out alias (both = d_out) -> no __restrict__ on them.
__global__ __launch_bounds__(256) void aggre_kernel(
    const float* __restrict__ prev_sum, const float* next_sum,
    const float* __restrict__ x, const float* __restrict__ w_next,
    const float* __restrict__ w_prev, const float* __restrict__ b,
    float* a_out, float* __restrict__ buckets) {
  __shared__ float pl[128][36];  // [k][row], pad 36: aligned float4, broadcast reads
  __shared__ float nl[128][36];
  __shared__ float rs[4][128];
  __shared__ float rq[4][128];
  int t = threadIdx.x;
  int r0 = blockIdx.x * 32;

#pragma unroll
  for (int i = 0; i < 16; ++i) {
    int idx = t + 256 * i;  // 0..4095
    int r = idx >> 7, k = idx & 127;
    pl[k][r] = prev_sum[(size_t)(r0 + r) * FDIM + k];
    nl[k][r] = next_sum[(size_t)(r0 + r) * FDIM + k];
  }
  __syncthreads();

  int c2 = t & 63;
  int ty = t >> 6;  // 0..3
  float acc0[8], acc1[8];
#pragma unroll
  for (int r = 0; r < 8; ++r) { acc0[r] = 0.f; acc1[r] = 0.f; }

  for (int k = 0; k < 128; ++k) {
    float4 p0 = *(const float4*)&pl[k][ty * 8];
    float4 p1 = *(const float4*)&pl[k][ty * 8 + 4];
    float4 n0 = *(const float4*)&nl[k][ty * 8];
    float4 n1 = *(const float4*)&nl[k][ty * 8 + 4];
    float wn0 = w_next[k * 128 + c2], wn1 = w_next[k * 128 + c2 + 64];
    float wp0 = w_prev[k * 128 + c2], wp1 = w_prev[k * 128 + c2 + 64];
    float pv[8] = {p0.x, p0.y, p0.z, p0.w, p1.x, p1.y, p1.z, p1.w};
    float nv[8] = {n0.x, n0.y, n0.z, n0.w, n1.x, n1.y, n1.z, n1.w};
#pragma unroll
    for (int r = 0; r < 8; ++r) {
      acc0[r] += nv[r] * wn0 + pv[r] * wp0;
      acc1[r] += nv[r] * wn1 + pv[r] * wp1;
    }
  }

  float b0 = b[c2], b1 = b[c2 + 64];
  float s1_0 = 0.f, s2_0 = 0.f, s1_1 = 0.f, s2_1 = 0.f;
#pragma unroll
  for (int r = 0; r < 8; ++r) {
    size_t row = (size_t)(r0 + ty * 8 + r) * FDIM;
    float v0 = acc0[r] + b0 + x[row + c2];
    float v1 = acc1[r] + b1 + x[row + c2 + 64];
    v0 = fmaxf(v0, 0.f);
    v1 = fmaxf(v1, 0.f);
    a_out[row + c2] = v0;
    a_out[row + c2 + 64] = v1;
    s1_0 += v0; s2_0 += v0 * v0;
    s1_1 += v1; s2_1 += v1 * v1;
  }
  rs[ty][c2] = s1_0; rs[ty][c2 + 64] = s1_1;
  rq[ty][c2] = s2_0; rq[ty][c2 + 64] = s2_1;
  __syncthreads();
  if (t < 128) {
    float s = rs[0][t] + rs[1][t] + rs[2][t] + rs[3][t];
    float q = rq[0][t] + rq[1][t] + rq[2][t] + rq[3][t];
    float* bkt = buckets + (size_t)(blockIdx.x & 63) * 256;
    atomicAdd(bkt + t, s);
    atomicAdd(bkt + 128 + t, q);
  }
}

// ---------------------------------------------------------------- BN finalize
__global__ void bn_finalize(const float* __restrict__ buckets,
                            const float* __restrict__ gamma,
                            const float* __restrict__ beta,
                            float* __restrict__ scaleshift) {
  int t = threadIdx.x;  // 128
  float s = 0.f, q = 0.f;
  for (int j = 0; j < 64; ++j) {
    s += buckets[j * 256 + t];
    q += buckets[j * 256 + 128 + t];
  }
  float mean = s / (float)N_NODES;
  float var = q / (float)N_NODES - mean * mean;
  var = fmaxf(var, 0.f);
  float sc = gamma[t] * rsqrtf(var + BN_EPS);
  scaleshift[t] = sc;
  scaleshift[128 + t] = beta[t] - mean * sc;
}

// ---------------------------------------------------------------- GRU
// block: 256 threads, 16 rows. thread: col c (gate triplet c,c+128,c+256), rows ty*8..+7
// a_buf and out alias (both = d_out): block reads its own rows before writing them.
__global__ __launch_bounds__(256) void gru_kernel_f(
    const float* a_buf, const float* __restrict__ x,
    const float* __restrict__ pg, const float* __restrict__ pr,
    const float* __restrict__ gbias, const float* __restrict__ scaleshift,
    float* out) {
  __shared__ float al[128][20];  // [k][row] anorm
  __shared__ float xl[128][20];  // [k][row] x
  int t = threadIdx.x;
  int r0 = blockIdx.x * 16;

#pragma unroll
  for (int i = 0; i < 8; ++i) {
    int idx = t + 256 * i;  // 0..2047
    int r = idx >> 7, k = idx & 127;
    float av = a_buf[(size_t)(r0 + r) * FDIM + k];
    al[k][r] = av * scaleshift[k] + scaleshift[128 + k];
    xl[k][r] = x[(size_t)(r0 + r) * FDIM + k];
  }
  __syncthreads();

  int c = t & 127;
  int ty = t >> 7;  // 0/1
  float mz[8], mr[8], mh[8], iz[8], ir[8], ih[8];
  float bz0 = gbias[c], br0 = gbias[128 + c], bh0 = gbias[256 + c];
  float bz1 = gbias[384 + c], br1 = gbias[512 + c], bh1 = gbias[640 + c];
#pragma unroll
  for (int r = 0; r < 8; ++r) {
    mz[r] = bz0; mr[r] = br0; mh[r] = bh0;
    iz[r] = bz1; ir[r] = br1; ih[r] = bh1;
  }

  for (int k = 0; k < 128; ++k) {
    float4 a0 = *(const float4*)&al[k][ty * 8];
    float4 a1 = *(const float4*)&al[k][ty * 8 + 4];
    float4 x0 = *(const float4*)&xl[k][ty * 8];
    float4 x1 = *(const float4*)&xl[k][ty * 8 + 4];
    float4 g = ((const float4*)pg)[k * 128 + c];
    float4 rw = ((const float4*)pr)[k * 128 + c];
    float av[8] = {a0.x, a0.y, a0.z, a0.w, a1.x, a1.y, a1.z, a1.w};
    float xv[8] = {x0.x, x0.y, x0.z, x0.w, x1.x, x1.y, x1.z, x1.w};
#pragma unroll
    for (int r = 0; r < 8; ++r) {
      mz[r] += av[r] * g.x;
      mr[r] += av[r] * g.y;
      mh[r] += av[r] * g.z;
      iz[r] += xv[r] * rw.x;
      ir[r] += xv[r] * rw.y;
      ih[r] += xv[r] * rw.z;
    }
  }

#pragma unroll
  for (int r = 0; r < 8; ++r) {
    int rl = ty * 8 + r;
    size_t row = (size_t)(r0 + rl) * FDIM;
    float z = 1.f / (1.f + __expf(-(mz[r] + iz[r])));
    float rg = 1.f / (1.f + __expf(-(mr[r] + ir[r])));
    float hc = tanhf(mh[r] + rg * ih[r]);
    float h = xl[c][rl];
    out[row + c] = z * h + (1.f - z) * hc;
  }
}

// ---------------------------------------------------------------- launch
extern "C" void kernel_launch(void* const* d_in, const int* in_sizes, int n_in,
                              void* d_out, int out_size, void* d_ws, size_t ws_size,
                              hipStream_t stream) {
  const float* x = (const float*)d_in[0];
  const int* pp = (const int*)d_in[1];
  const int* pn = (const int*)d_in[2];
  const float* w_next = (const float*)d_in[3];
  const float* w_prev = (const float*)d_in[4];
  const float* b = (const float*)d_in[5];
  const float* gamma = (const float*)d_in[6];
  const float* beta = (const float*)d_in[7];
  const float* gk = (const float*)d_in[8];
  const float* rk = (const float*)d_in[9];
  const float* gbias = (const float*)d_in[10];
  float* out = (float*)d_out;
  float* ws = (float*)d_ws;

  float* buckets = ws + WS_BUCKETS;
  float* scaleshift = ws + WS_SCALESHIFT;
  float* pg = ws + WS_PACK_GRU;
  float* pr = ws + WS_PACK_REC;
  float* prev_sum = ws + WS_PREV;
  float* next_sum = out;  // d_out triple-duty: next_sum -> a -> output

  size_t nf = (size_t)N_NODES * FDIM;
  hipMemsetAsync(d_out, 0, nf * sizeof(float), stream);
  hipMemsetAsync(buckets, 0, (16384 + 256) * sizeof(float), stream);
  hipMemsetAsync(prev_sum, 0, nf * sizeof(float), stream);

  repack_kernel<<<64, 256, 0, stream>>>(gk, rk, pg, pr);
  scatter_kernel<<<E_EDGES, 256, 0, stream>>>(pp, pn, x, prev_sum, next_sum);
  aggre_kernel<<<N_NODES / 32, 256, 0, stream>>>(prev_sum, next_sum, x, w_next,
                                                 w_prev, b, out, buckets);
  bn_finalize<<<1, 128, 0, stream>>>(buckets, gamma, beta, scaleshift);
  gru_kernel_f<<<N_NODES / 16, 256, 0, stream>>>(out, x, pg, pr, gbias,
                                                 scaleshift, out);
}

// Round 2
// 1530.201 us; speedup vs baseline: 1.8915x; 1.8915x over previous
//
#include <hip/hip_runtime.h>
#include <hip/hip_bf16.h>

#define N_NODES 500000
#define E_EDGES 500000
#define FDIM 128
#define BN_EPS 1e-3f

// ws layout (in floats):
//   [0, 16384)        buckets: 64 x (sum[128], sumsq[128])
//   [16384, 16640)    scaleshift: scale[128], shift[128]
//   [16640, 65792)    pw  (gru weights)  bf16 [2 side][3 gate][128 n][128 k]
//   [65792, 82176)    pw2 (aggre weights) bf16 [2 side][128 n][128 k]  side0=w_next
//   [82176, +64e6)    prev_sum [N][128] f32
#define WS_BUCKETS 0
#define WS_SCALESHIFT 16384
#define WS_PW 16640
#define WS_PW2 65792
#define WS_PREV 82176

typedef __attribute__((ext_vector_type(4))) float v4f;
typedef __attribute__((ext_vector_type(8))) __bf16 v8bf;

__device__ __forceinline__ unsigned f2bf_u(float f) {
  unsigned u = __float_as_uint(f);
  return ((u + 0x7FFF + ((u >> 16) & 1)) >> 16) & 0xFFFF;
}
__device__ __forceinline__ unsigned f2bf2(float a, float b) {
  return f2bf_u(a) | (f2bf_u(b) << 16);
}

// ---------------------------------------------------------------- weight repack
__global__ __launch_bounds__(256) void repack_gru(
    const float* __restrict__ gk, const float* __restrict__ rk,
    unsigned short* __restrict__ pw) {
  int idx = blockIdx.x * 256 + threadIdx.x;  // 0..98303
  int side = idx / 49152;
  int rem = idx % 49152;
  int gate = rem >> 14;
  int rr = rem & 16383;
  int c = rr >> 7, k = rr & 127;
  const float* src = side ? rk : gk;
  pw[idx] = (unsigned short)f2bf_u(src[k * 384 + gate * 128 + c]);
}

__global__ __launch_bounds__(256) void repack_w(
    const float* __restrict__ w_next, const float* __restrict__ w_prev,
    unsigned short* __restrict__ pw2) {
  int idx = blockIdx.x * 256 + threadIdx.x;  // 0..32767
  int side = idx >> 14;
  int rr = idx & 16383;
  int c = rr >> 7, k = rr & 127;
  const float* src = side ? w_prev : w_next;
  pw2[idx] = (unsigned short)f2bf_u(src[k * 128 + c]);
}

// ---------------------------------------------------------------- scatter-add
__global__ __launch_bounds__(256) void scatter_kernel(
    const int* __restrict__ pp, const int* __restrict__ pn,
    const float* __restrict__ x, float* prev_sum, float* next_sum) {
  int e = blockIdx.x * 2 + (threadIdx.x >> 7);
  int f = threadIdx.x & 127;
  const int* pair;
  float* dst;
  if (e < E_EDGES) {
    pair = pp + 2 * e;
    dst = prev_sum;
  } else {
    pair = pn + 2 * (e - E_EDGES);
    dst = next_sum;
  }
  int d = pair[0], s = pair[1];
  atomicAdd(dst + (size_t)d * FDIM + f, x[(size_t)s * FDIM + f]);
}

// ---------------------------------------------------------------- aggre (MFMA) + relu + BN-stats
// 32 rows/block, 4 waves. wave w: rows (w&1)*16..+15, cols (w>>1)*64..+63.
// a_out aliases next_sum (both d_out): block reads its rows to LDS, then overwrites.
__global__ __launch_bounds__(256) void aggre_mfma(
    const float* __restrict__ prev_sum, const float* next_sum,
    const float* __restrict__ x, const unsigned short* __restrict__ pw2,
    const float* __restrict__ b, float* a_out, float* __restrict__ buckets) {
  __shared__ unsigned short Ap[32 * 128];  // prev tile bf16, XOR-swizzled
  __shared__ unsigned short An[32 * 128];  // next tile
  __shared__ float rs[2][128];
  __shared__ float rq[2][128];
  int t = threadIdx.x;
  int r0 = blockIdx.x * 32;

#pragma unroll
  for (int i = 0; i < 4; ++i) {
    int q = t + 256 * i;              // 0..1023 float4-index
    int row = q >> 5, kq = q & 31;    // 32 float4 per row
    size_t g = (size_t)(r0 + row) * FDIM + kq * 4;
    float4 pv = *(const float4*)(prev_sum + g);
    float4 nv = *(const float4*)(next_sum + g);
    int byte = (row * 256 + kq * 8) ^ ((row & 7) << 4);
    *(uint2*)((char*)Ap + byte) = make_uint2(f2bf2(pv.x, pv.y), f2bf2(pv.z, pv.w));
    *(uint2*)((char*)An + byte) = make_uint2(f2bf2(nv.x, nv.y), f2bf2(nv.z, nv.w));
  }
  __syncthreads();

  int w = t >> 6, lane = t & 63;
  int m0 = (w & 1) * 16, nh = w >> 1;
  int l15 = lane & 15, lg = lane >> 4;

  v4f acc[4];
#pragma unroll
  for (int nb = 0; nb < 4; ++nb) acc[nb] = (v4f){0.f, 0.f, 0.f, 0.f};

#pragma unroll
  for (int ks = 0; ks < 4; ++ks) {
    int mm = m0 + l15;
    int byte = (mm * 256 + ks * 64 + lg * 16) ^ ((mm & 7) << 4);
    v8bf ap = __builtin_bit_cast(v8bf, *(const uint4*)((const char*)Ap + byte));
    v8bf an = __builtin_bit_cast(v8bf, *(const uint4*)((const char*)An + byte));
#pragma unroll
    for (int nb = 0; nb < 4; ++nb) {
      int n = nh * 64 + nb * 16 + l15;
      const unsigned short* q0 = pw2 + (size_t)n * 128 + ks * 32 + lg * 8;          // w_next
      const unsigned short* q1 = pw2 + 16384 + (size_t)n * 128 + ks * 32 + lg * 8;  // w_prev
      v8bf bn_ = __builtin_bit_cast(v8bf, *(const uint4*)q0);
      v8bf bp_ = __builtin_bit_cast(v8bf, *(const uint4*)q1);
      acc[nb] = __builtin_amdgcn_mfma_f32_16x16x32_bf16(an, bn_, acc[nb], 0, 0, 0);
      acc[nb] = __builtin_amdgcn_mfma_f32_16x16x32_bf16(ap, bp_, acc[nb], 0, 0, 0);
    }
  }

  float s1[4], s2[4];
#pragma unroll
  for (int nb = 0; nb < 4; ++nb) {
    int c = nh * 64 + nb * 16 + l15;
    float bb = b[c];
    s1[nb] = 0.f;
    s2[nb] = 0.f;
#pragma unroll
    for (int r = 0; r < 4; ++r) {
      int row = r0 + m0 + 4 * lg + r;
      size_t off = (size_t)row * FDIM + c;
      float v = acc[nb][r] + bb + x[off];
      v = fmaxf(v, 0.f);
      a_out[off] = v;
      s1[nb] += v;
      s2[nb] += v * v;
    }
    s1[nb] += __shfl_xor(s1[nb], 16);
    s1[nb] += __shfl_xor(s1[nb], 32);
    s2[nb] += __shfl_xor(s2[nb], 16);
    s2[nb] += __shfl_xor(s2[nb], 32);
  }
  if (lane < 16) {
#pragma unroll
    for (int nb = 0; nb < 4; ++nb) {
      rs[w & 1][nh * 64 + nb * 16 + lane] = s1[nb];
      rq[w & 1][nh * 64 + nb * 16 + lane] = s2[nb];
    }
  }
  __syncthreads();
  if (t < 128) {
    float s = rs[0][t] + rs[1][t];
    float q = rq[0][t] + rq[1][t];
    float* bkt = buckets + (size_t)(blockIdx.x & 63) * 256;
    atomicAdd(bkt + t, s);
    atomicAdd(bkt + 128 + t, q);
  }
}

// ---------------------------------------------------------------- BN finalize
__global__ void bn_finalize(const float* __restrict__ buckets,
                            const float* __restrict__ gamma,
                            const float* __restrict__ beta,
                            float* __restrict__ scaleshift) {
  int t = threadIdx.x;  // 128
  float s = 0.f, q = 0.f;
  for (int j = 0; j < 64; ++j) {
    s += buckets[j * 256 + t];
    q += buckets[j * 256 + 128 + t];
  }
  float mean = s / (float)N_NODES;
  float var = q / (float)N_NODES - mean * mean;
  var = fmaxf(var, 0.f);
  float sc = gamma[t] * rsqrtf(var + BN_EPS);
  scaleshift[t] = sc;
  scaleshift[128 + t] = beta[t] - mean * sc;
}

// ---------------------------------------------------------------- GRU (MFMA)
// 32 rows/block, 4 waves. wave w owns cols w*32..w*32+31 for all 3 gates, both GEMMs.
// a_buf and out alias (d_out): block stages its rows, then overwrites them.
__global__ __launch_bounds__(256) void gru_mfma(
    const float* a_buf, const float* __restrict__ x,
    const unsigned short* __restrict__ pw, const float* __restrict__ gbias,
    const float* __restrict__ scaleshift, float* out) {
  __shared__ unsigned short Aa[32 * 128];  // a_norm bf16, swizzled
  __shared__ unsigned short Ax[32 * 128];  // x bf16, swizzled
  int t = threadIdx.x;
  int r0 = blockIdx.x * 32;

#pragma unroll
  for (int i = 0; i < 4; ++i) {
    int q = t + 256 * i;
    int row = q >> 5, kq = q & 31;
    size_t g = (size_t)(r0 + row) * FDIM + kq * 4;
    float4 av = *(const float4*)(a_buf + g);
    float4 xv = *(const float4*)(x + g);
    float4 sc = *(const float4*)(scaleshift + kq * 4);
    float4 sh = *(const float4*)(scaleshift + 128 + kq * 4);
    float n0 = av.x * sc.x + sh.x, n1 = av.y * sc.y + sh.y;
    float n2 = av.z * sc.z + sh.z, n3 = av.w * sc.w + sh.w;
    int byte = (row * 256 + kq * 8) ^ ((row & 7) << 4);
    *(uint2*)((char*)Aa + byte) = make_uint2(f2bf2(n0, n1), f2bf2(n2, n3));
    *(uint2*)((char*)Ax + byte) = make_uint2(f2bf2(xv.x, xv.y), f2bf2(xv.z, xv.w));
  }
  __syncthreads();

  int w = t >> 6, lane = t & 63;
  int l15 = lane & 15, lg = lane >> 4;

  v4f acc[2][2][3][2];  // [m][nb][gate][side]
#pragma unroll
  for (int m = 0; m < 2; ++m)
#pragma unroll
    for (int nb = 0; nb < 2; ++nb)
#pragma unroll
      for (int g = 0; g < 3; ++g)
#pragma unroll
        for (int s = 0; s < 2; ++s) acc[m][nb][g][s] = (v4f){0.f, 0.f, 0.f, 0.f};

#pragma unroll
  for (int ks = 0; ks < 4; ++ks) {
    v8bf aa[2], ax[2];
#pragma unroll
    for (int m = 0; m < 2; ++m) {
      int mm = m * 16 + l15;
      int byte = (mm * 256 + ks * 64 + lg * 16) ^ ((mm & 7) << 4);
      aa[m] = __builtin_bit_cast(v8bf, *(const uint4*)((const char*)Aa + byte));
      ax[m] = __builtin_bit_cast(v8bf, *(const uint4*)((const char*)Ax + byte));
    }
#pragma unroll
    for (int nb = 0; nb < 2; ++nb) {
      int n = w * 32 + nb * 16 + l15;
#pragma unroll
      for (int g = 0; g < 3; ++g) {
        const unsigned short* p0 = pw + ((size_t)g * 128 + n) * 128 + ks * 32 + lg * 8;
        const unsigned short* p1 = pw + ((size_t)(3 + g) * 128 + n) * 128 + ks * 32 + lg * 8;
        v8bf b0 = __builtin_bit_cast(v8bf, *(const uint4*)p0);
        v8bf b1 = __builtin_bit_cast(v8bf, *(const uint4*)p1);
#pragma unroll
        for (int m = 0; m < 2; ++m) {
          acc[m][nb][g][0] =
              __builtin_amdgcn_mfma_f32_16x16x32_bf16(aa[m], b0, acc[m][nb][g][0], 0, 0, 0);
          acc[m][nb][g][1] =
              __builtin_amdgcn_mfma_f32_16x16x32_bf16(ax[m], b1, acc[m][nb][g][1], 0, 0, 0);
        }
      }
    }
  }

#pragma unroll
  for (int nb = 0; nb < 2; ++nb) {
    int c = w * 32 + nb * 16 + l15;
    float bz = gbias[c] + gbias[384 + c];
    float br = gbias[128 + c] + gbias[512 + c];
    float bh0 = gbias[256 + c];
    float bh1 = gbias[640 + c];
#pragma unroll
    for (int m = 0; m < 2; ++m) {
#pragma unroll
      for (int r = 0; r < 4; ++r) {
        int row = r0 + m * 16 + 4 * lg + r;
        size_t off = (size_t)row * FDIM + c;
        float z = 1.f / (1.f + __expf(-(acc[m][nb][0][0][r] + acc[m][nb][0][1][r] + bz)));
        float rg = 1.f / (1.f + __expf(-(acc[m][nb][1][0][r] + acc[m][nb][1][1][r] + br)));
        float hc = tanhf(acc[m][nb][2][0][r] + bh0 + rg * (acc[m][nb][2][1][r] + bh1));
        float h = x[off];
        out[off] = z * h + (1.f - z) * hc;
      }
    }
  }
}

// ---------------------------------------------------------------- launch
extern "C" void kernel_launch(void* const* d_in, const int* in_sizes, int n_in,
                              void* d_out, int out_size, void* d_ws, size_t ws_size,
                              hipStream_t stream) {
  const float* x = (const float*)d_in[0];
  const int* pp = (const int*)d_in[1];
  const int* pn = (const int*)d_in[2];
  const float* w_next = (const float*)d_in[3];
  const float* w_prev = (const float*)d_in[4];
  const float* b = (const float*)d_in[5];
  const float* gamma = (const float*)d_in[6];
  const float* beta = (const float*)d_in[7];
  const float* gk = (const float*)d_in[8];
  const float* rk = (const float*)d_in[9];
  const float* gbias = (const float*)d_in[10];
  float* out = (float*)d_out;
  float* ws = (float*)d_ws;

  float* buckets = ws + WS_BUCKETS;
  float* scaleshift = ws + WS_SCALESHIFT;
  unsigned short* pw = (unsigned short*)(ws + WS_PW);
  unsigned short* pw2 = (unsigned short*)(ws + WS_PW2);
  float* prev_sum = ws + WS_PREV;
  float* next_sum = out;  // d_out triple-duty: next_sum -> a -> output

  size_t nf = (size_t)N_NODES * FDIM;
  hipMemsetAsync(d_out, 0, nf * sizeof(float), stream);
  hipMemsetAsync(buckets, 0, (16384 + 256) * sizeof(float), stream);
  hipMemsetAsync(prev_sum, 0, nf * sizeof(float), stream);

  repack_gru<<<384, 256, 0, stream>>>(gk, rk, pw);
  repack_w<<<128, 256, 0, stream>>>(w_next, w_prev, pw2);
  scatter_kernel<<<E_EDGES, 256, 0, stream>>>(pp, pn, x, prev_sum, next_sum);
  aggre_mfma<<<N_NODES / 32, 256, 0, stream>>>(prev_sum, next_sum, x, pw2, b, out,
                                               buckets);
  bn_finalize<<<1, 128, 0, stream>>>(buckets, gamma, beta, scaleshift);
  gru_mfma<<<N_NODES / 32, 256, 0, stream>>>(out, x, pw, gbias, scaleshift, out);
}

// Round 3
// 1108.853 us; speedup vs baseline: 2.6102x; 1.3800x over previous
//
#include <hip/hip_runtime.h>
#include <hip/hip_bf16.h>

#define N_NODES 500000
#define E_EDGES 500000
#define FDIM 128
#define BN_EPS 1e-3f

// ws layout (in floats):
//   [0, 16384)        buckets: 64 x (sum[128], sumsq[128])
//   [16384, 16640)    scaleshift: scale[128], shift[128]
//   [16640, 65792)    pw  (gru weights)  bf16 fragment-order, 192 KB
//                       elem = w*24576 + ks*6144 + nb*3072 + g*1024 + side*512 + lane*8 + j
//   [65792, 82176)    pw2 (aggre weights) bf16 fragment-order, 64 KB
//                       elem = nh*16384 + ks*4096 + nb*1024 + side*512 + lane*8 + j
//   [82176, +64e6)    prev_sum [N][128] f32
#define WS_BUCKETS 0
#define WS_SCALESHIFT 16384
#define WS_PW 16640
#define WS_PW2 65792
#define WS_PREV 82176

typedef __attribute__((ext_vector_type(4))) float v4f;
typedef __attribute__((ext_vector_type(8))) __bf16 v8bf;

__device__ __forceinline__ unsigned f2bf_u(float f) {
  unsigned u = __float_as_uint(f);
  return ((u + 0x7FFF + ((u >> 16) & 1)) >> 16) & 0xFFFF;
}
__device__ __forceinline__ unsigned f2bf2(float a, float b) {
  return f2bf_u(a) | (f2bf_u(b) << 16);
}
__device__ __forceinline__ float fast_sigmoid(float x) {
  float e = __expf(-x);
  return __builtin_amdgcn_rcpf(1.f + e);
}
__device__ __forceinline__ float fast_tanh(float x) {
  x = fminf(fmaxf(x, -15.f), 15.f);
  float e = __expf(2.f * x);
  return (e - 1.f) * __builtin_amdgcn_rcpf(e + 1.f);
}

// ---------------------------------------------------------------- weight repack
// GRU weights -> MFMA B-fragment order: a wave's load is base + lane*16B (coalesced).
__global__ __launch_bounds__(256) void repack_gru(
    const float* __restrict__ gk, const float* __restrict__ rk,
    unsigned short* __restrict__ pw) {
  int idx = blockIdx.x * 256 + threadIdx.x;  // 0..98303
  int side = idx / 49152;
  int rem = idx % 49152;
  int gate = rem >> 14;
  int rr = rem & 16383;
  int c = rr >> 7, k = rr & 127;
  const float* src = side ? rk : gk;
  float v = src[k * 384 + gate * 128 + c];
  int w = c >> 5, nb = (c >> 4) & 1, l15 = c & 15;
  int ks = k >> 5, lg = (k >> 3) & 3, j = k & 7;
  int lane = lg * 16 + l15;
  int e = w * 24576 + ks * 6144 + nb * 3072 + gate * 1024 + side * 512 + lane * 8 + j;
  pw[e] = (unsigned short)f2bf_u(v);
}

__global__ __launch_bounds__(256) void repack_w(
    const float* __restrict__ w_next, const float* __restrict__ w_prev,
    unsigned short* __restrict__ pw2) {
  int idx = blockIdx.x * 256 + threadIdx.x;  // 0..32767
  int side = idx >> 14;
  int rr = idx & 16383;
  int c = rr >> 7, k = rr & 127;
  const float* src = side ? w_prev : w_next;
  float v = src[k * 128 + c];
  int nh = c >> 6, nb = (c >> 4) & 3, l15 = c & 15;
  int ks = k >> 5, lg = (k >> 3) & 3, j = k & 7;
  int lane = lg * 16 + l15;
  int e = nh * 16384 + ks * 4096 + nb * 1024 + side * 512 + lane * 8 + j;
  pw2[e] = (unsigned short)f2bf_u(v);
}

// ---------------------------------------------------------------- scatter-add
__global__ __launch_bounds__(256) void scatter_kernel(
    const int* __restrict__ pp, const int* __restrict__ pn,
    const float* __restrict__ x, float* prev_sum, float* next_sum) {
  int e = blockIdx.x * 2 + (threadIdx.x >> 7);
  int f = threadIdx.x & 127;
  const int* pair;
  float* dst;
  if (e < E_EDGES) {
    pair = pp + 2 * e;
    dst = prev_sum;
  } else {
    pair = pn + 2 * (e - E_EDGES);
    dst = next_sum;
  }
  int d = pair[0], s = pair[1];
  atomicAdd(dst + (size_t)d * FDIM + f, x[(size_t)s * FDIM + f]);
}

// ---------------------------------------------------------------- aggre (MFMA) + relu + BN-stats
// 32 rows/block, 4 waves. wave w: rows (w&1)*16..+15, cols (w>>1)*64..+63.
__global__ __launch_bounds__(256) void aggre_mfma(
    const float* __restrict__ prev_sum, const float* next_sum,
    const float* __restrict__ x, const unsigned short* __restrict__ pw2,
    const float* __restrict__ b, float* a_out, float* __restrict__ buckets) {
  __shared__ unsigned short Ap[32 * 128];  // prev tile bf16, XOR-swizzled
  __shared__ unsigned short An[32 * 128];  // next tile
  __shared__ float rs[2][128];
  __shared__ float rq[2][128];
  int t = threadIdx.x;
  int r0 = blockIdx.x * 32;

#pragma unroll
  for (int i = 0; i < 4; ++i) {
    int q = t + 256 * i;
    int row = q >> 5, kq = q & 31;
    size_t g = (size_t)(r0 + row) * FDIM + kq * 4;
    float4 pv = *(const float4*)(prev_sum + g);
    float4 nv = *(const float4*)(next_sum + g);
    int byte = (row * 256 + kq * 8) ^ ((row & 7) << 4);
    *(uint2*)((char*)Ap + byte) = make_uint2(f2bf2(pv.x, pv.y), f2bf2(pv.z, pv.w));
    *(uint2*)((char*)An + byte) = make_uint2(f2bf2(nv.x, nv.y), f2bf2(nv.z, nv.w));
  }
  __syncthreads();

  int w = t >> 6, lane = t & 63;
  int m0 = (w & 1) * 16, nh = w >> 1;
  int l15 = lane & 15, lg = lane >> 4;

  v4f acc[4];
#pragma unroll
  for (int nb = 0; nb < 4; ++nb) acc[nb] = (v4f){0.f, 0.f, 0.f, 0.f};

#pragma unroll
  for (int ks = 0; ks < 4; ++ks) {
    int mm = m0 + l15;
    int byte = (mm * 256 + ks * 64 + lg * 16) ^ ((mm & 7) << 4);
    v8bf ap = __builtin_bit_cast(v8bf, *(const uint4*)((const char*)Ap + byte));
    v8bf an = __builtin_bit_cast(v8bf, *(const uint4*)((const char*)An + byte));
    const unsigned short* wb = pw2 + nh * 16384 + ks * 4096 + lane * 8;
#pragma unroll
    for (int nb = 0; nb < 4; ++nb) {
      v8bf bn_ = __builtin_bit_cast(v8bf, *(const uint4*)(wb + nb * 1024));
      v8bf bp_ = __builtin_bit_cast(v8bf, *(const uint4*)(wb + nb * 1024 + 512));
      acc[nb] = __builtin_amdgcn_mfma_f32_16x16x32_bf16(an, bn_, acc[nb], 0, 0, 0);
      acc[nb] = __builtin_amdgcn_mfma_f32_16x16x32_bf16(ap, bp_, acc[nb], 0, 0, 0);
    }
  }

  float s1[4], s2[4];
#pragma unroll
  for (int nb = 0; nb < 4; ++nb) {
    int c = nh * 64 + nb * 16 + l15;
    float bb = b[c];
    s1[nb] = 0.f;
    s2[nb] = 0.f;
#pragma unroll
    for (int r = 0; r < 4; ++r) {
      int row = r0 + m0 + 4 * lg + r;
      size_t off = (size_t)row * FDIM + c;
      float v = acc[nb][r] + bb + x[off];
      v = fmaxf(v, 0.f);
      a_out[off] = v;
      s1[nb] += v;
      s2[nb] += v * v;
    }
    s1[nb] += __shfl_xor(s1[nb], 16);
    s1[nb] += __shfl_xor(s1[nb], 32);
    s2[nb] += __shfl_xor(s2[nb], 16);
    s2[nb] += __shfl_xor(s2[nb], 32);
  }
  if (lane < 16) {
#pragma unroll
    for (int nb = 0; nb < 4; ++nb) {
      rs[w & 1][nh * 64 + nb * 16 + lane] = s1[nb];
      rq[w & 1][nh * 64 + nb * 16 + lane] = s2[nb];
    }
  }
  __syncthreads();
  if (t < 128) {
    float s = rs[0][t] + rs[1][t];
    float q = rq[0][t] + rq[1][t];
    float* bkt = buckets + (size_t)(blockIdx.x & 63) * 256;
    atomicAdd(bkt + t, s);
    atomicAdd(bkt + 128 + t, q);
  }
}

// ---------------------------------------------------------------- BN finalize
__global__ void bn_finalize(const float* __restrict__ buckets,
                            const float* __restrict__ gamma,
                            const float* __restrict__ beta,
                            float* __restrict__ scaleshift) {
  int t = threadIdx.x;  // 128
  float s = 0.f, q = 0.f;
  for (int j = 0; j < 64; ++j) {
    s += buckets[j * 256 + t];
    q += buckets[j * 256 + 128 + t];
  }
  float mean = s / (float)N_NODES;
  float var = q / (float)N_NODES - mean * mean;
  var = fmaxf(var, 0.f);
  float sc = gamma[t] * rsqrtf(var + BN_EPS);
  scaleshift[t] = sc;
  scaleshift[128 + t] = beta[t] - mean * sc;
}

// ---------------------------------------------------------------- GRU (MFMA)
// 32 rows/block, 4 waves. wave w owns cols w*32..w*32+31 for all 3 gates, both GEMMs.
__global__ __launch_bounds__(256) void gru_mfma(
    const float* a_buf, const float* __restrict__ x,
    const unsigned short* __restrict__ pw, const float* __restrict__ gbias,
    const float* __restrict__ scaleshift, float* out) {
  __shared__ unsigned short Aa[32 * 128];  // a_norm bf16, swizzled
  __shared__ unsigned short Ax[32 * 128];  // x bf16, swizzled
  int t = threadIdx.x;
  int r0 = blockIdx.x * 32;

#pragma unroll
  for (int i = 0; i < 4; ++i) {
    int q = t + 256 * i;
    int row = q >> 5, kq = q & 31;
    size_t g = (size_t)(r0 + row) * FDIM + kq * 4;
    float4 av = *(const float4*)(a_buf + g);
    float4 xv = *(const float4*)(x + g);
    float4 sc = *(const float4*)(scaleshift + kq * 4);
    float4 sh = *(const float4*)(scaleshift + 128 + kq * 4);
    float n0 = av.x * sc.x + sh.x, n1 = av.y * sc.y + sh.y;
    float n2 = av.z * sc.z + sh.z, n3 = av.w * sc.w + sh.w;
    int byte = (row * 256 + kq * 8) ^ ((row & 7) << 4);
    *(uint2*)((char*)Aa + byte) = make_uint2(f2bf2(n0, n1), f2bf2(n2, n3));
    *(uint2*)((char*)Ax + byte) = make_uint2(f2bf2(xv.x, xv.y), f2bf2(xv.z, xv.w));
  }
  __syncthreads();

  int w = t >> 6, lane = t & 63;
  int l15 = lane & 15, lg = lane >> 4;

  v4f acc[2][2][3][2];  // [m][nb][gate][side]
#pragma unroll
  for (int m = 0; m < 2; ++m)
#pragma unroll
    for (int nb = 0; nb < 2; ++nb)
#pragma unroll
      for (int g = 0; g < 3; ++g)
#pragma unroll
        for (int s = 0; s < 2; ++s) acc[m][nb][g][s] = (v4f){0.f, 0.f, 0.f, 0.f};

#pragma unroll
  for (int ks = 0; ks < 4; ++ks) {
    v8bf aa[2], ax[2];
#pragma unroll
    for (int m = 0; m < 2; ++m) {
      int mm = m * 16 + l15;
      int byte = (mm * 256 + ks * 64 + lg * 16) ^ ((mm & 7) << 4);
      aa[m] = __builtin_bit_cast(v8bf, *(const uint4*)((const char*)Aa + byte));
      ax[m] = __builtin_bit_cast(v8bf, *(const uint4*)((const char*)Ax + byte));
    }
    const unsigned short* wb = pw + w * 24576 + ks * 6144 + lane * 8;
#pragma unroll
    for (int nb = 0; nb < 2; ++nb) {
#pragma unroll
      for (int g = 0; g < 3; ++g) {
        v8bf b0 = __builtin_bit_cast(v8bf, *(const uint4*)(wb + nb * 3072 + g * 1024));
        v8bf b1 = __builtin_bit_cast(v8bf, *(const uint4*)(wb + nb * 3072 + g * 1024 + 512));
#pragma unroll
        for (int m = 0; m < 2; ++m) {
          acc[m][nb][g][0] =
              __builtin_amdgcn_mfma_f32_16x16x32_bf16(aa[m], b0, acc[m][nb][g][0], 0, 0, 0);
          acc[m][nb][g][1] =
              __builtin_amdgcn_mfma_f32_16x16x32_bf16(ax[m], b1, acc[m][nb][g][1], 0, 0, 0);
        }
      }
    }
  }

#pragma unroll
  for (int nb = 0; nb < 2; ++nb) {
    int c = w * 32 + nb * 16 + l15;
    float bz = gbias[c] + gbias[384 + c];
    float br = gbias[128 + c] + gbias[512 + c];
    float bh0 = gbias[256 + c];
    float bh1 = gbias[640 + c];
#pragma unroll
    for (int m = 0; m < 2; ++m) {
#pragma unroll
      for (int r = 0; r < 4; ++r) {
        int row = r0 + m * 16 + 4 * lg + r;
        size_t off = (size_t)row * FDIM + c;
        float z = fast_sigmoid(acc[m][nb][0][0][r] + acc[m][nb][0][1][r] + bz);
        float rg = fast_sigmoid(acc[m][nb][1][0][r] + acc[m][nb][1][1][r] + br);
        float hc = fast_tanh(acc[m][nb][2][0][r] + bh0 + rg * (acc[m][nb][2][1][r] + bh1));
        float h = x[off];
        out[off] = z * h + (1.f - z) * hc;
      }
    }
  }
}

// ---------------------------------------------------------------- launch
extern "C" void kernel_launch(void* const* d_in, const int* in_sizes, int n_in,
                              void* d_out, int out_size, void* d_ws, size_t ws_size,
                              hipStream_t stream) {
  const float* x = (const float*)d_in[0];
  const int* pp = (const int*)d_in[1];
  const int* pn = (const int*)d_in[2];
  const float* w_next = (const float*)d_in[3];
  const float* w_prev = (const float*)d_in[4];
  const float* b = (const float*)d_in[5];
  const float* gamma = (const float*)d_in[6];
  const float* beta = (const float*)d_in[7];
  const float* gk = (const float*)d_in[8];
  const float* rk = (const float*)d_in[9];
  const float* gbias = (const float*)d_in[10];
  float* out = (float*)d_out;
  float* ws = (float*)d_ws;

  float* buckets = ws + WS_BUCKETS;
  float* scaleshift = ws + WS_SCALESHIFT;
  unsigned short* pw = (unsigned short*)(ws + WS_PW);
  unsigned short* pw2 = (unsigned short*)(ws + WS_PW2);
  float* prev_sum = ws + WS_PREV;
  float* next_sum = out;  // d_out triple-duty: next_sum -> a -> output

  size_t nf = (size_t)N_NODES * FDIM;
  hipMemsetAsync(d_out, 0, nf * sizeof(float), stream);
  hipMemsetAsync(buckets, 0, (16384 + 256) * sizeof(float), stream);
  hipMemsetAsync(prev_sum, 0, nf * sizeof(float), stream);

  repack_gru<<<384, 256, 0, stream>>>(gk, rk, pw);
  repack_w<<<128, 256, 0, stream>>>(w_next, w_prev, pw2);
  scatter_kernel<<<E_EDGES, 256, 0, stream>>>(pp, pn, x, prev_sum, next_sum);
  aggre_mfma<<<N_NODES / 32, 256, 0, stream>>>(prev_sum, next_sum, x, pw2, b, out,
                                               buckets);
  bn_finalize<<<1, 128, 0, stream>>>(buckets, gamma, beta, scaleshift);
  gru_mfma<<<N_NODES / 32, 256, 0, stream>>>(out, x, pw, gbias, scaleshift, out);
}

// Round 4
// 1073.397 us; speedup vs baseline: 2.6964x; 1.0330x over previous
//
#include <hip/hip_runtime.h>
#include <hip/hip_bf16.h>

#define N_NODES 500000
#define E_EDGES 500000
#define FDIM 128
#define BN_EPS 1e-3f
#define OFFS 500001  // per-side stride of the offsets array

// ws layout (in floats):
//   [0, 16384)        buckets: 64 x (sum[128], sumsq[128])
//   [16384, 16640)    scaleshift: scale[128], shift[128]
//   [16640, 65792)    pw  (gru weights)  bf16 fragment-order, 192 KB
//   [65792, 82176)    pw2 (aggre weights) bf16 fragment-order, 64 KB
//   [82176, ...)      prev_bf [N][128] bf16 (128 MB), then next_bf [N][128] bf16 (128 MB)
#define WS_BUCKETS 0
#define WS_SCALESHIFT 16384
#define WS_PW 16640
#define WS_PW2 65792
#define WS_PREV 82176

// d_out u32 scratch layout (valid until aggre_mfma overwrites d_out):
//   CNT  at 0         : u32[2][500000]
//   OFF  at 1000000   : u32[2][500001]
//   PART at 2100000   : u32[2][512]
//   CUR  at 2200000   : u32[2][500000]
//   SRC  at 3200000   : u32[2][500000]
#define SO_CNT 0
#define SO_OFF 1000000
#define SO_PART 2100000
#define SO_CUR 2200000
#define SO_SRC 3200000

typedef __attribute__((ext_vector_type(4))) float v4f;
typedef __attribute__((ext_vector_type(8))) __bf16 v8bf;

__device__ __forceinline__ unsigned f2bf_u(float f) {
  unsigned u = __float_as_uint(f);
  return ((u + 0x7FFF + ((u >> 16) & 1)) >> 16) & 0xFFFF;
}
__device__ __forceinline__ unsigned f2bf2(float a, float b) {
  return f2bf_u(a) | (f2bf_u(b) << 16);
}
__device__ __forceinline__ float fast_sigmoid(float x) {
  float e = __expf(-x);
  return __builtin_amdgcn_rcpf(1.f + e);
}
__device__ __forceinline__ float fast_tanh(float x) {
  x = fminf(fmaxf(x, -15.f), 15.f);
  float e = __expf(2.f * x);
  return (e - 1.f) * __builtin_amdgcn_rcpf(e + 1.f);
}

// ---------------------------------------------------------------- weight repack
__global__ __launch_bounds__(256) void repack_gru(
    const float* __restrict__ gk, const float* __restrict__ rk,
    unsigned short* __restrict__ pw) {
  int idx = blockIdx.x * 256 + threadIdx.x;  // 0..98303
  int side = idx / 49152;
  int rem = idx % 49152;
  int gate = rem >> 14;
  int rr = rem & 16383;
  int c = rr >> 7, k = rr & 127;
  const float* src = side ? rk : gk;
  float v = src[k * 384 + gate * 128 + c];
  int w = c >> 5, nb = (c >> 4) & 1, l15 = c & 15;
  int ks = k >> 5, lg = (k >> 3) & 3, j = k & 7;
  int lane = lg * 16 + l15;
  int e = w * 24576 + ks * 6144 + nb * 3072 + gate * 1024 + side * 512 + lane * 8 + j;
  pw[e] = (unsigned short)f2bf_u(v);
}

__global__ __launch_bounds__(256) void repack_w(
    const float* __restrict__ w_next, const float* __restrict__ w_prev,
    unsigned short* __restrict__ pw2) {
  int idx = blockIdx.x * 256 + threadIdx.x;  // 0..32767
  int side = idx >> 14;
  int rr = idx & 16383;
  int c = rr >> 7, k = rr & 127;
  const float* src = side ? w_prev : w_next;
  float v = src[k * 128 + c];
  int nh = c >> 6, nb = (c >> 4) & 3, l15 = c & 15;
  int ks = k >> 5, lg = (k >> 3) & 3, j = k & 7;
  int lane = lg * 16 + l15;
  int e = nh * 16384 + ks * 4096 + nb * 1024 + side * 512 + lane * 8 + j;
  pw2[e] = (unsigned short)f2bf_u(v);
}

// ---------------------------------------------------------------- CSR build
__global__ __launch_bounds__(256) void hist_kernel(const int* __restrict__ pp,
                                                   const int* __restrict__ pn,
                                                   unsigned* __restrict__ cnt) {
  int i = blockIdx.x * 256 + threadIdx.x;
  if (i >= 2 * E_EDGES) return;
  int side = i >= E_EDGES;
  const int* pair = side ? pn + 2 * (i - E_EDGES) : pp + 2 * i;
  atomicAdd(&cnt[side * N_NODES + pair[0]], 1u);
}

// block scans 1024 counts (256 thr x 4), writes local-exclusive offs + block total
__global__ __launch_bounds__(256) void scan1_kernel(const unsigned* __restrict__ cnt,
                                                    unsigned* __restrict__ off,
                                                    unsigned* __restrict__ part) {
  __shared__ unsigned ls[256];
  int side = blockIdx.y;
  int b = blockIdx.x;
  int td = threadIdx.x;
  int base = b * 1024 + td * 4;
  const unsigned* c = cnt + (size_t)side * N_NODES;
  unsigned v0 = 0, v1 = 0, v2 = 0, v3 = 0;
  if (base + 3 < N_NODES) {
    v0 = c[base]; v1 = c[base + 1]; v2 = c[base + 2]; v3 = c[base + 3];
  } else {
    if (base < N_NODES) v0 = c[base];
    if (base + 1 < N_NODES) v1 = c[base + 1];
    if (base + 2 < N_NODES) v2 = c[base + 2];
  }
  unsigned s = v0 + v1 + v2 + v3;
  ls[td] = s;
  __syncthreads();
  unsigned run = s;
  for (int st = 1; st < 256; st <<= 1) {
    unsigned o = (td >= st) ? ls[td - st] : 0u;
    __syncthreads();
    run += o;
    ls[td] = run;
    __syncthreads();
  }
  unsigned excl = run - s;
  unsigned* oo = off + (size_t)side * OFFS;
  if (base < N_NODES) oo[base] = excl;
  if (base + 1 < N_NODES) oo[base + 1] = excl + v0;
  if (base + 2 < N_NODES) oo[base + 2] = excl + v0 + v1;
  if (base + 3 < N_NODES) oo[base + 3] = excl + v0 + v1 + v2;
  if (td == 255) part[side * 512 + b] = run;
}

// single block: exclusive-scan the 2x512 block totals (sides independent)
__global__ __launch_bounds__(1024) void scan2_kernel(unsigned* __restrict__ part) {
  __shared__ unsigned ls[1024];
  int td = threadIdx.x;
  int b = td & 511;
  unsigned s = part[td];
  ls[td] = s;
  __syncthreads();
  unsigned run = s;
  for (int st = 1; st < 512; st <<= 1) {
    unsigned o = (b >= st) ? ls[td - st] : 0u;
    __syncthreads();
    run += o;
    ls[td] = run;
    __syncthreads();
  }
  part[td] = run - s;
}

// add scanned block totals; also init cursor array and the sentinel off[N]
__global__ __launch_bounds__(256) void scan3_kernel(unsigned* __restrict__ off,
                                                    const unsigned* __restrict__ part,
                                                    unsigned* __restrict__ cur) {
  int side = blockIdx.y;
  int i = blockIdx.x * 256 + threadIdx.x;
  if (i < N_NODES) {
    unsigned v = off[(size_t)side * OFFS + i] + part[side * 512 + (i >> 10)];
    off[(size_t)side * OFFS + i] = v;
    cur[(size_t)side * N_NODES + i] = v;
  }
  if (i == 0) off[(size_t)side * OFFS + N_NODES] = E_EDGES;
}

__global__ __launch_bounds__(256) void reorder_kernel(const int* __restrict__ pp,
                                                      const int* __restrict__ pn,
                                                      unsigned* __restrict__ cur,
                                                      unsigned* __restrict__ srcbuf) {
  int i = blockIdx.x * 256 + threadIdx.x;
  if (i >= 2 * E_EDGES) return;
  int side = i >= E_EDGES;
  const int* pair = side ? pn + 2 * (i - E_EDGES) : pp + 2 * i;
  unsigned pos = atomicAdd(&cur[(size_t)side * N_NODES + pair[0]], 1u);
  srcbuf[(size_t)side * E_EDGES + pos] = (unsigned)pair[1];
}

// ---------------------------------------------------------------- gather (segment sum)
// grid (N/2, 2): block = 2 dest rows x 128 threads; side = blockIdx.y
__global__ __launch_bounds__(256) void gather_kernel(
    const float* __restrict__ x, const unsigned* __restrict__ off,
    const unsigned* __restrict__ srcbuf, unsigned short* __restrict__ prev_bf,
    unsigned short* __restrict__ next_bf) {
  int side = blockIdx.y;
  int r = blockIdx.x * 2 + (threadIdx.x >> 7);
  int f = threadIdx.x & 127;
  const unsigned* oo = off + (size_t)side * OFFS;
  unsigned s0 = oo[r], s1 = oo[r + 1];
  const unsigned* sl = srcbuf + (size_t)side * E_EDGES;
  float acc = 0.f;
  for (unsigned i = s0; i < s1; ++i)
    acc += x[(size_t)sl[i] * FDIM + f];
  unsigned short* dst = side ? next_bf : prev_bf;
  dst[(size_t)r * FDIM + f] = (unsigned short)f2bf_u(acc);
}

// ---------------------------------------------------------------- aggre (MFMA) + relu + BN-stats
// 32 rows/block, 4 waves. wave w: rows (w&1)*16..+15, cols (w>>1)*64..+63.
__global__ __launch_bounds__(256) void aggre_mfma(
    const unsigned short* __restrict__ prev_bf, const unsigned short* __restrict__ next_bf,
    const float* __restrict__ x, const unsigned short* __restrict__ pw2,
    const float* __restrict__ b, float* __restrict__ a_out,
    float* __restrict__ buckets) {
  __shared__ unsigned short Ap[32 * 128];  // prev tile bf16, XOR-swizzled
  __shared__ unsigned short An[32 * 128];  // next tile
  __shared__ float rs[2][128];
  __shared__ float rq[2][128];
  int t = threadIdx.x;
  int r0 = blockIdx.x * 32;

#pragma unroll
  for (int i = 0; i < 2; ++i) {
    int q = t + 256 * i;             // 0..511 : 32 rows x 16 16B-groups
    int row = q >> 4, kq = q & 15;
    size_t g = (size_t)(r0 + row) * FDIM + kq * 8;
    uint4 pv = *(const uint4*)(prev_bf + g);
    uint4 nv = *(const uint4*)(next_bf + g);
    int byte = (row * 256 + kq * 16) ^ ((row & 7) << 4);
    *(uint4*)((char*)Ap + byte) = pv;
    *(uint4*)((char*)An + byte) = nv;
  }
  __syncthreads();

  int w = t >> 6, lane = t & 63;
  int m0 = (w & 1) * 16, nh = w >> 1;
  int l15 = lane & 15, lg = lane >> 4;

  v4f acc[4];
#pragma unroll
  for (int nb = 0; nb < 4; ++nb) acc[nb] = (v4f){0.f, 0.f, 0.f, 0.f};

#pragma unroll
  for (int ks = 0; ks < 4; ++ks) {
    int mm = m0 + l15;
    int byte = (mm * 256 + ks * 64 + lg * 16) ^ ((mm & 7) << 4);
    v8bf ap = __builtin_bit_cast(v8bf, *(const uint4*)((const char*)Ap + byte));
    v8bf an = __builtin_bit_cast(v8bf, *(const uint4*)((const char*)An + byte));
    const unsigned short* wb = pw2 + nh * 16384 + ks * 4096 + lane * 8;
#pragma unroll
    for (int nb = 0; nb < 4; ++nb) {
      v8bf bn_ = __builtin_bit_cast(v8bf, *(const uint4*)(wb + nb * 1024));
      v8bf bp_ = __builtin_bit_cast(v8bf, *(const uint4*)(wb + nb * 1024 + 512));
      acc[nb] = __builtin_amdgcn_mfma_f32_16x16x32_bf16(an, bn_, acc[nb], 0, 0, 0);
      acc[nb] = __builtin_amdgcn_mfma_f32_16x16x32_bf16(ap, bp_, acc[nb], 0, 0, 0);
    }
  }

  float s1[4], s2[4];
#pragma unroll
  for (int nb = 0; nb < 4; ++nb) {
    int c = nh * 64 + nb * 16 + l15;
    float bb = b[c];
    s1[nb] = 0.f;
    s2[nb] = 0.f;
#pragma unroll
    for (int r = 0; r < 4; ++r) {
      int row = r0 + m0 + 4 * lg + r;
      size_t off = (size_t)row * FDIM + c;
      float v = acc[nb][r] + bb + x[off];
      v = fmaxf(v, 0.f);
      a_out[off] = v;
      s1[nb] += v;
      s2[nb] += v * v;
    }
    s1[nb] += __shfl_xor(s1[nb], 16);
    s1[nb] += __shfl_xor(s1[nb], 32);
    s2[nb] += __shfl_xor(s2[nb], 16);
    s2[nb] += __shfl_xor(s2[nb], 32);
  }
  if (lane < 16) {
#pragma unroll
    for (int nb = 0; nb < 4; ++nb) {
      rs[w & 1][nh * 64 + nb * 16 + lane] = s1[nb];
      rq[w & 1][nh * 64 + nb * 16 + lane] = s2[nb];
    }
  }
  __syncthreads();
  if (t < 128) {
    float s = rs[0][t] + rs[1][t];
    float q = rq[0][t] + rq[1][t];
    float* bkt = buckets + (size_t)(blockIdx.x & 63) * 256;
    atomicAdd(bkt + t, s);
    atomicAdd(bkt + 128 + t, q);
  }
}

// ---------------------------------------------------------------- BN finalize
__global__ void bn_finalize(const float* __restrict__ buckets,
                            const float* __restrict__ gamma,
                            const float* __restrict__ beta,
                            float* __restrict__ scaleshift) {
  int t = threadIdx.x;  // 128
  float s = 0.f, q = 0.f;
  for (int j = 0; j < 64; ++j) {
    s += buckets[j * 256 + t];
    q += buckets[j * 256 + 128 + t];
  }
  float mean = s / (float)N_NODES;
  float var = q / (float)N_NODES - mean * mean;
  var = fmaxf(var, 0.f);
  float sc = gamma[t] * rsqrtf(var + BN_EPS);
  scaleshift[t] = sc;
  scaleshift[128 + t] = beta[t] - mean * sc;
}

// ---------------------------------------------------------------- GRU (MFMA)
// 32 rows/block, 4 waves. a_buf and out alias (d_out): block stages rows, then overwrites.
__global__ __launch_bounds__(256) void gru_mfma(
    const float* a_buf, const float* __restrict__ x,
    const unsigned short* __restrict__ pw, const float* __restrict__ gbias,
    const float* __restrict__ scaleshift, float* out) {
  __shared__ unsigned short Aa[32 * 128];  // a_norm bf16, swizzled
  __shared__ unsigned short Ax[32 * 128];  // x bf16, swizzled
  int t = threadIdx.x;
  int r0 = blockIdx.x * 32;

#pragma unroll
  for (int i = 0; i < 4; ++i) {
    int q = t + 256 * i;
    int row = q >> 5, kq = q & 31;
    size_t g = (size_t)(r0 + row) * FDIM + kq * 4;
    float4 av = *(const float4*)(a_buf + g);
    float4 xv = *(const float4*)(x + g);
    float4 sc = *(const float4*)(scaleshift + kq * 4);
    float4 sh = *(const float4*)(scaleshift + 128 + kq * 4);
    float n0 = av.x * sc.x + sh.x, n1 = av.y * sc.y + sh.y;
    float n2 = av.z * sc.z + sh.z, n3 = av.w * sc.w + sh.w;
    int byte = (row * 256 + kq * 8) ^ ((row & 7) << 4);
    *(uint2*)((char*)Aa + byte) = make_uint2(f2bf2(n0, n1), f2bf2(n2, n3));
    *(uint2*)((char*)Ax + byte) = make_uint2(f2bf2(xv.x, xv.y), f2bf2(xv.z, xv.w));
  }
  __syncthreads();

  int w = t >> 6, lane = t & 63;
  int l15 = lane & 15, lg = lane >> 4;

  v4f acc[2][2][3][2];  // [m][nb][gate][side]
#pragma unroll
  for (int m = 0; m < 2; ++m)
#pragma unroll
    for (int nb = 0; nb < 2; ++nb)
#pragma unroll
      for (int g = 0; g < 3; ++g)
#pragma unroll
        for (int s = 0; s < 2; ++s) acc[m][nb][g][s] = (v4f){0.f, 0.f, 0.f, 0.f};

#pragma unroll
  for (int ks = 0; ks < 4; ++ks) {
    v8bf aa[2], ax[2];
#pragma unroll
    for (int m = 0; m < 2; ++m) {
      int mm = m * 16 + l15;
      int byte = (mm * 256 + ks * 64 + lg * 16) ^ ((mm & 7) << 4);
      aa[m] = __builtin_bit_cast(v8bf, *(const uint4*)((const char*)Aa + byte));
      ax[m] = __builtin_bit_cast(v8bf, *(const uint4*)((const char*)Ax + byte));
    }
    const unsigned short* wb = pw + w * 24576 + ks * 6144 + lane * 8;
#pragma unroll
    for (int nb = 0; nb < 2; ++nb) {
#pragma unroll
      for (int g = 0; g < 3; ++g) {
        v8bf b0 = __builtin_bit_cast(v8bf, *(const uint4*)(wb + nb * 3072 + g * 1024));
        v8bf b1 = __builtin_bit_cast(v8bf, *(const uint4*)(wb + nb * 3072 + g * 1024 + 512));
#pragma unroll
        for (int m = 0; m < 2; ++m) {
          acc[m][nb][g][0] =
              __builtin_amdgcn_mfma_f32_16x16x32_bf16(aa[m], b0, acc[m][nb][g][0], 0, 0, 0);
          acc[m][nb][g][1] =
              __builtin_amdgcn_mfma_f32_16x16x32_bf16(ax[m], b1, acc[m][nb][g][1], 0, 0, 0);
        }
      }
    }
  }

#pragma unroll
  for (int nb = 0; nb < 2; ++nb) {
    int c = w * 32 + nb * 16 + l15;
    float bz = gbias[c] + gbias[384 + c];
    float br = gbias[128 + c] + gbias[512 + c];
    float bh0 = gbias[256 + c];
    float bh1 = gbias[640 + c];
#pragma unroll
    for (int m = 0; m < 2; ++m) {
#pragma unroll
      for (int r = 0; r < 4; ++r) {
        int row = r0 + m * 16 + 4 * lg + r;
        size_t off = (size_t)row * FDIM + c;
        float z = fast_sigmoid(acc[m][nb][0][0][r] + acc[m][nb][0][1][r] + bz);
        float rg = fast_sigmoid(acc[m][nb][1][0][r] + acc[m][nb][1][1][r] + br);
        float hc = fast_tanh(acc[m][nb][2][0][r] + bh0 + rg * (acc[m][nb][2][1][r] + bh1));
        float h = x[off];
        out[off] = z * h + (1.f - z) * hc;
      }
    }
  }
}

// ---------------------------------------------------------------- launch
extern "C" void kernel_launch(void* const* d_in, const int* in_sizes, int n_in,
                              void* d_out, int out_size, void* d_ws, size_t ws_size,
                              hipStream_t stream) {
  const float* x = (const float*)d_in[0];
  const int* pp = (const int*)d_in[1];
  const int* pn = (const int*)d_in[2];
  const float* w_next = (const float*)d_in[3];
  const float* w_prev = (const float*)d_in[4];
  const float* b = (const float*)d_in[5];
  const float* gamma = (const float*)d_in[6];
  const float* beta = (const float*)d_in[7];
  const float* gk = (const float*)d_in[8];
  const float* rk = (const float*)d_in[9];
  const float* gbias = (const float*)d_in[10];
  float* out = (float*)d_out;
  float* ws = (float*)d_ws;

  float* buckets = ws + WS_BUCKETS;
  float* scaleshift = ws + WS_SCALESHIFT;
  unsigned short* pw = (unsigned short*)(ws + WS_PW);
  unsigned short* pw2 = (unsigned short*)(ws + WS_PW2);
  unsigned short* prev_bf = (unsigned short*)(ws + WS_PREV);
  unsigned short* next_bf = prev_bf + (size_t)N_NODES * FDIM;

  unsigned* u = (unsigned*)d_out;
  unsigned* cnt = u + SO_CNT;
  unsigned* off = u + SO_OFF;
  unsigned* part = u + SO_PART;
  unsigned* cur = u + SO_CUR;
  unsigned* srcbuf = u + SO_SRC;

  hipMemsetAsync(cnt, 0, 2u * N_NODES * sizeof(unsigned), stream);
  hipMemsetAsync(part, 0, 1024 * sizeof(unsigned), stream);
  hipMemsetAsync(buckets, 0, (16384 + 256) * sizeof(float), stream);

  repack_gru<<<384, 256, 0, stream>>>(gk, rk, pw);
  repack_w<<<128, 256, 0, stream>>>(w_next, w_prev, pw2);

  hist_kernel<<<(2 * E_EDGES + 255) / 256, 256, 0, stream>>>(pp, pn, cnt);
  scan1_kernel<<<dim3(489, 2), 256, 0, stream>>>(cnt, off, part);
  scan2_kernel<<<1, 1024, 0, stream>>>(part);
  scan3_kernel<<<dim3((N_NODES + 255) / 256, 2), 256, 0, stream>>>(off, part, cur);
  reorder_kernel<<<(2 * E_EDGES + 255) / 256, 256, 0, stream>>>(pp, pn, cur, srcbuf);
  gather_kernel<<<dim3(N_NODES / 2, 2), 256, 0, stream>>>(x, off, srcbuf, prev_bf,
                                                          next_bf);

  aggre_mfma<<<N_NODES / 32, 256, 0, stream>>>(prev_bf, next_bf, x, pw2, b, out,
                                               buckets);
  bn_finalize<<<1, 128, 0, stream>>>(buckets, gamma, beta, scaleshift);
  gru_mfma<<<N_NODES / 32, 256, 0, stream>>>(out, x, pw, gbias, scaleshift, out);
}

// Round 6
// 762.797 us; speedup vs baseline: 3.7943x; 1.4072x over previous
//
#include <hip/hip_runtime.h>
#include <hip/hip_bf16.h>

#define N_NODES 500000
#define E_EDGES 500000
#define FDIM 128
#define BN_EPS 1e-3f
#define OFFS 500001  // per-side stride of the offsets array
#define GCAP 128    // edges staged per chunk in gather

// ws layout (in floats):
//   [0, 16384)        buckets: 64 x (sum[128], sumsq[128])
//   [16384, 16640)    scaleshift: scale[128], shift[128]
//   [16640, 65792)    pw  (gru weights)  bf16 fragment-order, 192 KB
//   [65792, 82176)    pw2 (aggre weights) bf16 fragment-order, 64 KB
//   [82176, ...)      prev_bf [N][128] bf16 (128 MB), then next_bf [N][128] bf16
//   a_bf ALIASES prev_bf (aggre reads its rows to LDS before overwriting them).
#define WS_BUCKETS 0
#define WS_SCALESHIFT 16384
#define WS_PW 16640
#define WS_PW2 65792
#define WS_PREV 82176

// d_out u32 scratch layout (dead once gru_mfma writes d_out at the very end):
//   CNT  at 0         : u32[2][500000]
//   OFF  at 1000000   : u32[2][500001]
//   PART at 2100000   : u32[2][512]
//   CUR  at 2200000   : u32[2][500000]
//   SRC  at 3200000   : u32[2][500000]   (ends at 16.8 MB)
//   XBF  at 6000000   : bf16[N][128]     (24 MB .. 152 MB; read by gather+aggre)
#define SO_CNT 0
#define SO_OFF 1000000
#define SO_PART 2100000
#define SO_CUR 2200000
#define SO_SRC 3200000
#define SO_XBF 6000000

typedef __attribute__((ext_vector_type(4))) float v4f;
typedef __attribute__((ext_vector_type(8))) __bf16 v8bf;

__device__ __forceinline__ unsigned f2bf_u(float f) {
  unsigned u = __float_as_uint(f);
  return ((u + 0x7FFF + ((u >> 16) & 1)) >> 16) & 0xFFFF;
}
__device__ __forceinline__ unsigned f2bf2(float a, float b) {
  return f2bf_u(a) | (f2bf_u(b) << 16);
}
__device__ __forceinline__ float bf2f(unsigned short u) {
  return __uint_as_float((unsigned)u << 16);
}
__device__ __forceinline__ float fast_sigmoid(float x) {
  float e = __expf(-x);
  return __builtin_amdgcn_rcpf(1.f + e);
}
__device__ __forceinline__ float fast_tanh(float x) {
  x = fminf(fmaxf(x, -15.f), 15.f);
  float e = __expf(2.f * x);
  return (e - 1.f) * __builtin_amdgcn_rcpf(e + 1.f);
}

// ---------------------------------------------------------------- weight repack
__global__ __launch_bounds__(256) void repack_gru(
    const float* __restrict__ gk, const float* __restrict__ rk,
    unsigned short* __restrict__ pw) {
  int idx = blockIdx.x * 256 + threadIdx.x;  // 0..98303
  int side = idx / 49152;
  int rem = idx % 49152;
  int gate = rem >> 14;
  int rr = rem & 16383;
  int c = rr >> 7, k = rr & 127;
  const float* src = side ? rk : gk;
  float v = src[k * 384 + gate * 128 + c];
  int w = c >> 5, nb = (c >> 4) & 1, l15 = c & 15;
  int ks = k >> 5, lg = (k >> 3) & 3, j = k & 7;
  int lane = lg * 16 + l15;
  int e = w * 24576 + ks * 6144 + nb * 3072 + gate * 1024 + side * 512 + lane * 8 + j;
  pw[e] = (unsigned short)f2bf_u(v);
}

__global__ __launch_bounds__(256) void repack_w(
    const float* __restrict__ w_next, const float* __restrict__ w_prev,
    unsigned short* __restrict__ pw2) {
  int idx = blockIdx.x * 256 + threadIdx.x;  // 0..32767
  int side = idx >> 14;
  int rr = idx & 16383;
  int c = rr >> 7, k = rr & 127;
  const float* src = side ? w_prev : w_next;
  float v = src[k * 128 + c];
  int nh = c >> 6, nb = (c >> 4) & 3, l15 = c & 15;
  int ks = k >> 5, lg = (k >> 3) & 3, j = k & 7;
  int lane = lg * 16 + l15;
  int e = nh * 16384 + ks * 4096 + nb * 1024 + side * 512 + lane * 8 + j;
  pw2[e] = (unsigned short)f2bf_u(v);
}

// ---------------------------------------------------------------- x -> bf16
__global__ __launch_bounds__(256) void xbf_kernel(const float* __restrict__ x,
                                                  unsigned short* __restrict__ xbf) {
  size_t i = ((size_t)blockIdx.x * 256 + threadIdx.x) * 8;
  if (i >= (size_t)N_NODES * FDIM) return;
  float4 a = *(const float4*)(x + i);
  float4 b = *(const float4*)(x + i + 4);
  uint4 o = make_uint4(f2bf2(a.x, a.y), f2bf2(a.z, a.w), f2bf2(b.x, b.y),
                       f2bf2(b.z, b.w));
  *(uint4*)(xbf + i) = o;
}

// ---------------------------------------------------------------- CSR build
__global__ __launch_bounds__(256) void hist_kernel(const int* __restrict__ pp,
                                                   const int* __restrict__ pn,
                                                   unsigned* __restrict__ cnt) {
  int i = blockIdx.x * 256 + threadIdx.x;
  if (i >= 2 * E_EDGES) return;
  int side = i >= E_EDGES;
  const int* pair = side ? pn + 2 * (i - E_EDGES) : pp + 2 * i;
  atomicAdd(&cnt[side * N_NODES + pair[0]], 1u);
}

__global__ __launch_bounds__(256) void scan1_kernel(const unsigned* __restrict__ cnt,
                                                    unsigned* __restrict__ off,
                                                    unsigned* __restrict__ part) {
  __shared__ unsigned ls[256];
  int side = blockIdx.y;
  int b = blockIdx.x;
  int td = threadIdx.x;
  int base = b * 1024 + td * 4;
  const unsigned* c = cnt + (size_t)side * N_NODES;
  unsigned v0 = 0, v1 = 0, v2 = 0, v3 = 0;
  if (base + 3 < N_NODES) {
    v0 = c[base]; v1 = c[base + 1]; v2 = c[base + 2]; v3 = c[base + 3];
  } else {
    if (base < N_NODES) v0 = c[base];
    if (base + 1 < N_NODES) v1 = c[base + 1];
    if (base + 2 < N_NODES) v2 = c[base + 2];
  }
  unsigned s = v0 + v1 + v2 + v3;
  ls[td] = s;
  __syncthreads();
  unsigned run = s;
  for (int st = 1; st < 256; st <<= 1) {
    unsigned o = (td >= st) ? ls[td - st] : 0u;
    __syncthreads();
    run += o;
    ls[td] = run;
    __syncthreads();
  }
  unsigned excl = run - s;
  unsigned* oo = off + (size_t)side * OFFS;
  if (base < N_NODES) oo[base] = excl;
  if (base + 1 < N_NODES) oo[base + 1] = excl + v0;
  if (base + 2 < N_NODES) oo[base + 2] = excl + v0 + v1;
  if (base + 3 < N_NODES) oo[base + 3] = excl + v0 + v1 + v2;
  if (td == 255) part[side * 512 + b] = run;
}

__global__ __launch_bounds__(1024) void scan2_kernel(unsigned* __restrict__ part) {
  __shared__ unsigned ls[1024];
  int td = threadIdx.x;
  int b = td & 511;
  unsigned s = part[td];
  ls[td] = s;
  __syncthreads();
  unsigned run = s;
  for (int st = 1; st < 512; st <<= 1) {
    unsigned o = (b >= st) ? ls[td - st] : 0u;
    __syncthreads();
    run += o;
    ls[td] = run;
    __syncthreads();
  }
  part[td] = run - s;
}

__global__ __launch_bounds__(256) void scan3_kernel(unsigned* __restrict__ off,
                                                    const unsigned* __restrict__ part,
                                                    unsigned* __restrict__ cur) {
  int side = blockIdx.y;
  int i = blockIdx.x * 256 + threadIdx.x;
  if (i < N_NODES) {
    unsigned v = off[(size_t)side * OFFS + i] + part[side * 512 + (i >> 10)];
    off[(size_t)side * OFFS + i] = v;
    cur[(size_t)side * N_NODES + i] = v;
  }
  if (i == 0) off[(size_t)side * OFFS + N_NODES] = E_EDGES;
}

__global__ __launch_bounds__(256) void reorder_kernel(const int* __restrict__ pp,
                                                      const int* __restrict__ pn,
                                                      unsigned* __restrict__ cur,
                                                      unsigned* __restrict__ srcbuf) {
  int i = blockIdx.x * 256 + threadIdx.x;
  if (i >= 2 * E_EDGES) return;
  int side = i >= E_EDGES;
  const int* pair = side ? pn + 2 * (i - E_EDGES) : pp + 2 * i;
  unsigned pos = atomicAdd(&cur[(size_t)side * N_NODES + pair[0]], 1u);
  srcbuf[(size_t)side * E_EDGES + pos] = (unsigned)pair[1];
}

// ---------------------------------------------------------------- gather (segment sum)
// grid (N/32, 2): block = 32 dest rows. Edge-parallel LDS staging (high MLP),
// then per-row register accumulation. xbf is bf16 (128 MB -> L3-resident).
__global__ __launch_bounds__(256) void gather_kernel(
    const unsigned short* __restrict__ xbf, const unsigned* __restrict__ off,
    const unsigned* __restrict__ srcbuf, unsigned short* __restrict__ prev_bf,
    unsigned short* __restrict__ next_bf) {
  __shared__ unsigned short stage[GCAP][128];  // 32 KB
  __shared__ unsigned soff[33];
  __shared__ unsigned ssrc[GCAP];
  int side = blockIdx.y;
  int r0 = blockIdx.x * 32;
  int t = threadIdx.x;
  const unsigned* oo = off + (size_t)side * OFFS + r0;
  if (t < 33) soff[t] = oo[t];
  __syncthreads();
  unsigned e0 = soff[0], e1 = soff[32];
  const unsigned* sl = srcbuf + (size_t)side * E_EDGES;

  float acc[16];
#pragma unroll
  for (int i = 0; i < 16; ++i) acc[i] = 0.f;
  int rr = t >> 3, fc = t & 7;  // my row, my 16-feature chunk

  for (unsigned base = e0; base < e1; base += GCAP) {
    unsigned cnt = min((unsigned)GCAP, e1 - base);
    if (t < cnt) ssrc[t] = sl[base + t];
    __syncthreads();
    // stage: group g (32 lanes) copies edge rows base+g, base+g+8, ...
    int g = t >> 5, ld = t & 31;
    for (unsigned j = g; j < cnt; j += 8) {
      size_t s = ssrc[j];
      uint2 v = *(const uint2*)(xbf + s * FDIM + ld * 4);
      *(uint2*)&stage[j][ld * 4] = v;
    }
    __syncthreads();
    // accumulate my row's edges within this chunk
    unsigned rs = soff[rr] > base ? soff[rr] : base;
    unsigned re = soff[rr + 1] < base + GCAP ? soff[rr + 1] : base + GCAP;
    for (unsigned i = rs; i < re; ++i) {
      uint4 u0 = *(const uint4*)&stage[i - base][fc * 16];
      uint4 u1 = *(const uint4*)&stage[i - base][fc * 16 + 8];
      acc[0] += bf2f((unsigned short)(u0.x & 0xffff)); acc[1] += __uint_as_float(u0.x & 0xffff0000u);
      acc[2] += bf2f((unsigned short)(u0.y & 0xffff)); acc[3] += __uint_as_float(u0.y & 0xffff0000u);
      acc[4] += bf2f((unsigned short)(u0.z & 0xffff)); acc[5] += __uint_as_float(u0.z & 0xffff0000u);
      acc[6] += bf2f((unsigned short)(u0.w & 0xffff)); acc[7] += __uint_as_float(u0.w & 0xffff0000u);
      acc[8] += bf2f((unsigned short)(u1.x & 0xffff)); acc[9] += __uint_as_float(u1.x & 0xffff0000u);
      acc[10] += bf2f((unsigned short)(u1.y & 0xffff)); acc[11] += __uint_as_float(u1.y & 0xffff0000u);
      acc[12] += bf2f((unsigned short)(u1.z & 0xffff)); acc[13] += __uint_as_float(u1.z & 0xffff0000u);
      acc[14] += bf2f((unsigned short)(u1.w & 0xffff)); acc[15] += __uint_as_float(u1.w & 0xffff0000u);
    }
    __syncthreads();
  }

  unsigned short* dst = (side ? next_bf : prev_bf) + (size_t)(r0 + rr) * FDIM + fc * 16;
  uint4 o0 = make_uint4(f2bf2(acc[0], acc[1]), f2bf2(acc[2], acc[3]),
                        f2bf2(acc[4], acc[5]), f2bf2(acc[6], acc[7]));
  uint4 o1 = make_uint4(f2bf2(acc[8], acc[9]), f2bf2(acc[10], acc[11]),
                        f2bf2(acc[12], acc[13]), f2bf2(acc[14], acc[15]));
  *(uint4*)dst = o0;
  *(uint4*)(dst + 8) = o1;
}

// ---------------------------------------------------------------- aggre (MFMA) + relu + BN-stats
// 32 rows/block, 4 waves. wave w: rows (w&1)*16..+15, cols (w>>1)*64..+63.
// a_out (bf16) ALIASES prev_bf: block reads its rows to LDS before overwriting.
__global__ __launch_bounds__(256) void aggre_mfma(
    const unsigned short* prev_bf, const unsigned short* __restrict__ next_bf,
    const unsigned short* __restrict__ xbf, const unsigned short* __restrict__ pw2,
    const float* __restrict__ b, unsigned short* a_out,
    float* __restrict__ buckets) {
  __shared__ unsigned short Ap[32 * 128];  // prev tile bf16, XOR-swizzled
  __shared__ unsigned short An[32 * 128];  // next tile
  __shared__ float rs[2][128];
  __shared__ float rq[2][128];
  int t = threadIdx.x;
  int r0 = blockIdx.x * 32;

#pragma unroll
  for (int i = 0; i < 2; ++i) {
    int q = t + 256 * i;  // 0..511 : 32 rows x 16 16B-groups
    int row = q >> 4, kq = q & 15;
    size_t g = (size_t)(r0 + row) * FDIM + kq * 8;
    uint4 pv = *(const uint4*)(prev_bf + g);
    uint4 nv = *(const uint4*)(next_bf + g);
    int byte = (row * 256 + kq * 16) ^ ((row & 7) << 4);
    *(uint4*)((char*)Ap + byte) = pv;
    *(uint4*)((char*)An + byte) = nv;
  }
  __syncthreads();

  int w = t >> 6, lane = t & 63;
  int m0 = (w & 1) * 16, nh = w >> 1;
  int l15 = lane & 15, lg = lane >> 4;

  v4f acc[4];
#pragma unroll
  for (int nb = 0; nb < 4; ++nb) acc[nb] = (v4f){0.f, 0.f, 0.f, 0.f};

#pragma unroll
  for (int ks = 0; ks < 4; ++ks) {
    int mm = m0 + l15;
    int byte = (mm * 256 + ks * 64 + lg * 16) ^ ((mm & 7) << 4);
    v8bf ap = __builtin_bit_cast(v8bf, *(const uint4*)((const char*)Ap + byte));
    v8bf an = __builtin_bit_cast(v8bf, *(const uint4*)((const char*)An + byte));
    const unsigned short* wb = pw2 + nh * 16384 + ks * 4096 + lane * 8;
#pragma unroll
    for (int nb = 0; nb < 4; ++nb) {
      v8bf bn_ = __builtin_bit_cast(v8bf, *(const uint4*)(wb + nb * 1024));
      v8bf bp_ = __builtin_bit_cast(v8bf, *(const uint4*)(wb + nb * 1024 + 512));
      acc[nb] = __builtin_amdgcn_mfma_f32_16x16x32_bf16(an, bn_, acc[nb], 0, 0, 0);
      acc[nb] = __builtin_amdgcn_mfma_f32_16x16x32_bf16(ap, bp_, acc[nb], 0, 0, 0);
    }
  }

  float s1[4], s2[4];
#pragma unroll
  for (int nb = 0; nb < 4; ++nb) {
    int c = nh * 64 + nb * 16 + l15;
    float bb = b[c];
    s1[nb] = 0.f;
    s2[nb] = 0.f;
#pragma unroll
    for (int r = 0; r < 4; ++r) {
      int row = r0 + m0 + 4 * lg + r;
      size_t off = (size_t)row * FDIM + c;
      float v = acc[nb][r] + bb + bf2f(xbf[off]);
      v = fmaxf(v, 0.f);
      a_out[off] = (unsigned short)f2bf_u(v);
      s1[nb] += v;
      s2[nb] += v * v;
    }
    s1[nb] += __shfl_xor(s1[nb], 16);
    s1[nb] += __shfl_xor(s1[nb], 32);
    s2[nb] += __shfl_xor(s2[nb], 16);
    s2[nb] += __shfl_xor(s2[nb], 32);
  }
  if (lane < 16) {
#pragma unroll
    for (int nb = 0; nb < 4; ++nb) {
      rs[w & 1][nh * 64 + nb * 16 + lane] = s1[nb];
      rq[w & 1][nh * 64 + nb * 16 + lane] = s2[nb];
    }
  }
  __syncthreads();
  if (t < 128) {
    float s = rs[0][t] + rs[1][t];
    float q = rq[0][t] + rq[1][t];
    float* bkt = buckets + (size_t)(blockIdx.x & 63) * 256;
    atomicAdd(bkt + t, s);
    atomicAdd(bkt + 128 + t, q);
  }
}

// ---------------------------------------------------------------- BN finalize
__global__ void bn_finalize(const float* __restrict__ buckets,
                            const float* __restrict__ gamma,
                            const float* __restrict__ beta,
                            float* __restrict__ scaleshift) {
  int t = threadIdx.x;  // 128
  float s = 0.f, q = 0.f;
  for (int j = 0; j < 64; ++j) {
    s += buckets[j * 256 + t];
    q += buckets[j * 256 + 128 + t];
  }
  float mean = s / (float)N_NODES;
  float var = q / (float)N_NODES - mean * mean;
  var = fmaxf(var, 0.f);
  float sc = gamma[t] * rsqrtf(var + BN_EPS);
  scaleshift[t] = sc;
  scaleshift[128 + t] = beta[t] - mean * sc;
}

// ---------------------------------------------------------------- GRU (MFMA)
// 32 rows/block, 4 waves. a from a_bf (bf16); h and staging x from f32 x.
__global__ __launch_bounds__(256) void gru_mfma(
    const unsigned short* __restrict__ a_bf, const float* __restrict__ x,
    const unsigned short* __restrict__ pw, const float* __restrict__ gbias,
    const float* __restrict__ scaleshift, float* __restrict__ out) {
  __shared__ unsigned short Aa[32 * 128];  // a_norm bf16, swizzled
  __shared__ unsigned short Ax[32 * 128];  // x bf16, swizzled
  int t = threadIdx.x;
  int r0 = blockIdx.x * 32;

#pragma unroll
  for (int i = 0; i < 2; ++i) {
    int q = t + 256 * i;  // 0..511 : 32 rows x 16 groups of 8 feats
    int row = q >> 4, kq = q & 15;
    size_t g = (size_t)(r0 + row) * FDIM + kq * 8;
    uint4 av = *(const uint4*)(a_bf + g);  // 8 bf16
    float4 x0 = *(const float4*)(x + g);
    float4 x1 = *(const float4*)(x + g + 4);
    float4 sc0 = *(const float4*)(scaleshift + kq * 8);
    float4 sc1 = *(const float4*)(scaleshift + kq * 8 + 4);
    float4 sh0 = *(const float4*)(scaleshift + 128 + kq * 8);
    float4 sh1 = *(const float4*)(scaleshift + 128 + kq * 8 + 4);
    float a0 = __uint_as_float(av.x << 16), a1 = __uint_as_float(av.x & 0xffff0000u);
    float a2 = __uint_as_float(av.y << 16), a3 = __uint_as_float(av.y & 0xffff0000u);
    float a4 = __uint_as_float(av.z << 16), a5 = __uint_as_float(av.z & 0xffff0000u);
    float a6 = __uint_as_float(av.w << 16), a7 = __uint_as_float(av.w & 0xffff0000u);
    uint4 na = make_uint4(f2bf2(a0 * sc0.x + sh0.x, a1 * sc0.y + sh0.y),
                          f2bf2(a2 * sc0.z + sh0.z, a3 * sc0.w + sh0.w),
                          f2bf2(a4 * sc1.x + sh1.x, a5 * sc1.y + sh1.y),
                          f2bf2(a6 * sc1.z + sh1.z, a7 * sc1.w + sh1.w));
    uint4 nx = make_uint4(f2bf2(x0.x, x0.y), f2bf2(x0.z, x0.w),
                          f2bf2(x1.x, x1.y), f2bf2(x1.z, x1.w));
    int byte = (row * 256 + kq * 16) ^ ((row & 7) << 4);
    *(uint4*)((char*)Aa + byte) = na;
    *(uint4*)((char*)Ax + byte) = nx;
  }
  __syncthreads();

  int w = t >> 6, lane = t & 63;
  int l15 = lane & 15, lg = lane >> 4;

  v4f acc[2][2][3][2];  // [m][nb][gate][side]
#pragma unroll
  for (int m = 0; m < 2; ++m)
#pragma unroll
    for (int nb = 0; nb < 2; ++nb)
#pragma unroll
      for (int g = 0; g < 3; ++g)
#pragma unroll
        for (int s = 0; s < 2; ++s) acc[m][nb][g][s] = (v4f){0.f, 0.f, 0.f, 0.f};

#pragma unroll
  for (int ks = 0; ks < 4; ++ks) {
    v8bf aa[2], ax[2];
#pragma unroll
    for (int m = 0; m < 2; ++m) {
      int mm = m * 16 + l15;
      int byte = (mm * 256 + ks * 64 + lg * 16) ^ ((mm & 7) << 4);
      aa[m] = __builtin_bit_cast(v8bf, *(const uint4*)((const char*)Aa + byte));
      ax[m] = __builtin_bit_cast(v8bf, *(const uint4*)((const char*)Ax + byte));
    }
    const unsigned short* wb = pw + w * 24576 + ks * 6144 + lane * 8;
#pragma unroll
    for (int nb = 0; nb < 2; ++nb) {
#pragma unroll
      for (int g = 0; g < 3; ++g) {
        v8bf b0 = __builtin_bit_cast(v8bf, *(const uint4*)(wb + nb * 3072 + g * 1024));
        v8bf b1 = __builtin_bit_cast(v8bf, *(const uint4*)(wb + nb * 3072 + g * 1024 + 512));
#pragma unroll
        for (int m = 0; m < 2; ++m) {
          acc[m][nb][g][0] =
              __builtin_amdgcn_mfma_f32_16x16x32_bf16(aa[m], b0, acc[m][nb][g][0], 0, 0, 0);
          acc[m][nb][g][1] =
              __builtin_amdgcn_mfma_f32_16x16x32_bf16(ax[m], b1, acc[m][nb][g][1], 0, 0, 0);
        }
      }
    }
  }

#pragma unroll
  for (int nb = 0; nb < 2; ++nb) {
    int c = w * 32 + nb * 16 + l15;
    float bz = gbias[c] + gbias[384 + c];
    float br = gbias[128 + c] + gbias[512 + c];
    float bh0 = gbias[256 + c];
    float bh1 = gbias[640 + c];
#pragma unroll
    for (int m = 0; m < 2; ++m) {
#pragma unroll
      for (int r = 0; r < 4; ++r) {
        int row = r0 + m * 16 + 4 * lg + r;
        size_t off = (size_t)row * FDIM + c;
        float z = fast_sigmoid(acc[m][nb][0][0][r] + acc[m][nb][0][1][r] + bz);
        float rg = fast_sigmoid(acc[m][nb][1][0][r] + acc[m][nb][1][1][r] + br);
        float hc = fast_tanh(acc[m][nb][2][0][r] + bh0 + rg * (acc[m][nb][2][1][r] + bh1));
        float h = x[off];
        out[off] = z * h + (1.f - z) * hc;
      }
    }
  }
}

// ---------------------------------------------------------------- launch
extern "C" void kernel_launch(void* const* d_in, const int* in_sizes, int n_in,
                              void* d_out, int out_size, void* d_ws, size_t ws_size,
                              hipStream_t stream) {
  const float* x = (const float*)d_in[0];
  const int* pp = (const int*)d_in[1];
  const int* pn = (const int*)d_in[2];
  const float* w_next = (const float*)d_in[3];
  const float* w_prev = (const float*)d_in[4];
  const float* b = (const float*)d_in[5];
  const float* gamma = (const float*)d_in[6];
  const float* beta = (const float*)d_in[7];
  const float* gk = (const float*)d_in[8];
  const float* rk = (const float*)d_in[9];
  const float* gbias = (const float*)d_in[10];
  float* out = (float*)d_out;
  float* ws = (float*)d_ws;

  float* buckets = ws + WS_BUCKETS;
  float* scaleshift = ws + WS_SCALESHIFT;
  unsigned short* pw = (unsigned short*)(ws + WS_PW);
  unsigned short* pw2 = (unsigned short*)(ws + WS_PW2);
  unsigned short* prev_bf = (unsigned short*)(ws + WS_PREV);
  unsigned short* next_bf = prev_bf + (size_t)N_NODES * FDIM;
  unsigned short* a_bf = prev_bf;  // alias: aggre reads rows before overwriting

  unsigned* u = (unsigned*)d_out;
  unsigned* cnt = u + SO_CNT;
  unsigned* off = u + SO_OFF;
  unsigned* part = u + SO_PART;
  unsigned* cur = u + SO_CUR;
  unsigned* srcbuf = u + SO_SRC;
  unsigned short* xbf = (unsigned short*)(u + SO_XBF);  // dead before gru writes out

  hipMemsetAsync(cnt, 0, 2u * N_NODES * sizeof(unsigned), stream);
  hipMemsetAsync(part, 0, 1024 * sizeof(unsigned), stream);
  hipMemsetAsync(buckets, 0, (16384 + 256) * sizeof(float), stream);

  repack_gru<<<384, 256, 0, stream>>>(gk, rk, pw);
  repack_w<<<128, 256, 0, stream>>>(w_next, w_prev, pw2);
  // 64e6 floats / (256 threads * 8 floats) = 31250 blocks exactly
  xbf_kernel<<<31250, 256, 0, stream>>>(x, xbf);

  hist_kernel<<<(2 * E_EDGES + 255) / 256, 256, 0, stream>>>(pp, pn, cnt);
  scan1_kernel<<<dim3(489, 2), 256, 0, stream>>>(cnt, off, part);
  scan2_kernel<<<1, 1024, 0, stream>>>(part);
  scan3_kernel<<<dim3((N_NODES + 255) / 256, 2), 256, 0, stream>>>(off, part, cur);
  reorder_kernel<<<(2 * E_EDGES + 255) / 256, 256, 0, stream>>>(pp, pn, cur, srcbuf);
  gather_kernel<<<dim3(N_NODES / 32, 2), 256, 0, stream>>>(xbf, off, srcbuf, prev_bf,
                                                           next_bf);

  aggre_mfma<<<N_NODES / 32, 256, 0, stream>>>(prev_bf, next_bf, xbf, pw2, b, a_bf,
                                               buckets);
  bn_finalize<<<1, 128, 0, stream>>>(buckets, gamma, beta, scaleshift);
  gru_mfma<<<N_NODES / 32, 256, 0, stream>>>(a_bf, x, pw, gbias, scaleshift, out);
}